// Round 3
// baseline (201.581 us; speedup 1.0000x reference)
//
#include <hip/hip_runtime.h>

#define EPSF 1e-20f

constexpr int B_ = 2, C_ = 32, O_ = 32, H_ = 256, W_ = 512;
constexpr int HO = 254, WO = 510;
constexpr int SEG  = 62;                      // valid outputs per wave (64 lanes)
constexpr int NSEG = (WO + SEG - 1) / SEG;    // 9
constexpr int NWAVE = B_ * HO * NSEG;         // 4572 wave-jobs
constexpr long OUT1 = (long)B_ * O_ * HO * WO;

__device__ __forceinline__ float sp_(float x) { return log1pf(expf(x)); }

// ---------------------------------------------------------------------------
// Setup: softplus all learned weights + reductions, into params buffer.
// Layout (floats): [0]=w  [1]=sum(sw)  [2]=sum(cw)  [16..304)=sw(288)
//                  [304..1328)=cw(1024)
// ---------------------------------------------------------------------------
__global__ __launch_bounds__(256) void k_setup(const float* __restrict__ w_prop,
                                               const float* __restrict__ spw,
                                               const float* __restrict__ chw,
                                               float* __restrict__ params) {
  __shared__ float red[256];
  int t = threadIdx.x;
  float l1 = 0.f;
  for (int i = t; i < 288; i += 256) { float v = sp_(spw[i]); params[16 + i] = v; l1 += v; }
  red[t] = l1; __syncthreads();
  for (int k = 128; k > 0; k >>= 1) { if (t < k) red[t] += red[t + k]; __syncthreads(); }
  float SW = red[0]; __syncthreads();
  float l2 = 0.f;
  for (int i = t; i < 1024; i += 256) { float v = sp_(chw[i]); params[304 + i] = v; l2 += v; }
  red[t] = l2; __syncthreads();
  for (int k = 128; k > 0; k >>= 1) { if (t < k) red[t] += red[t + k]; __syncthreads(); }
  if (t == 0) { params[0] = sp_(w_prop[0]); params[1] = SW; params[2] = red[0]; }
}

// ---------------------------------------------------------------------------
// Wave-autonomous fused kernel. One wave = one (b, ho, 62-wide col segment).
// Stage-1 gy_f/cgy_f in registers (3 patch rows per lane-column), column
// neighbors via __shfl_down. 3x3 grouped conv + 1x1 channel mix accumulated
// in 64 regs. Zero barriers in the channel loop.
// ---------------------------------------------------------------------------
__global__ __launch_bounds__(256, 3) void k_fused(const float* __restrict__ d,
                                                  const float* __restrict__ cd,
                                                  const float* __restrict__ s,
                                                  const float* __restrict__ gy,
                                                  const float* __restrict__ cgy,
                                                  const float* __restrict__ spr,
                                                  const float* __restrict__ params,
                                                  const float* __restrict__ bias,
                                                  float* __restrict__ out) {
  __shared__ float sw_s[288];
  __shared__ float cw_s[1024];
  __shared__ float bias_s[O_];

  const int t = threadIdx.x;
  for (int i = t; i < 288; i += 256)  sw_s[i] = params[16 + i];
  for (int i = t; i < 1024; i += 256) cw_s[i] = params[304 + i];
  if (t < O_) bias_s[t] = bias[t];
  const float w      = params[0];
  const float inv_w1 = 1.0f / (w + 1.0f);
  const float invSW  = 1.0f / params[1];
  const float invCW  = 1.0f / params[2];
  __syncthreads();  // the only block barrier

  const int lane = t & 63;
  const int wid  = blockIdx.x * 4 + (t >> 6);
  if (wid >= NWAVE) return;
  const int b    = wid / (HO * NSEG);
  const int rem  = wid - b * (HO * NSEG);
  const int ho   = rem / NSEG;
  const int seg  = rem - ho * NSEG;
  const int wo0  = seg * SEG;
  const int wo   = wo0 + lane;
  const int gw   = (wo < W_) ? wo : (W_ - 1);       // clamped image col (stage-1)
  const int wo_c = (wo < WO) ? wo : (WO - 1);       // clamped output col (spr addr)
  const bool valid = (lane < SEG) && (wo < WO);

  float n2[O_], d2[O_];
#pragma unroll
  for (int o = 0; o < O_; ++o) { n2[o] = 0.f; d2[o] = 0.f; }

  for (int c = 0; c < C_; ++c) {
    const long cpl = (long)(b * C_ + c) * H_ * W_;

    // ---- load vertical strip: rows ho-1 .. ho+3 ----
    float dv[5], sv[5], cdv[5];
#pragma unroll
    for (int m = 0; m < 5; ++m) {
      const int row = ho - 1 + m;
      const int rw  = (row < 0) ? row + H_ : ((row >= H_) ? row - H_ : row);
      const long a  = cpl + (long)rw * W_ + gw;
      dv[m] = d[a];
      sv[m] = s[a];
      cdv[m] = (row < 0 || row >= H_) ? 0.f : cd[cpl + (long)row * W_ + gw];
    }

    // ---- stage-1: gy_f / cgy_f at rows ho..ho+2 for this lane's column ----
    float gf[3], cf[3];
#pragma unroll
    for (int r = 0; r < 3; ++r) {
      const float cu  = cdv[r];
      const float cdn = cdv[r + 2];
      const float du  = dv[r], dd = dv[r + 2];
      const long  ga  = cpl + (long)(ho + r) * W_ + gw;
      const float cfd    = sv[r + 1] * sv[r] * sv[r + 2] * cu * cu;  // cd_up twice
      const float height = (cu * du + cdn * dd) / (cu + cdn + EPSF);
      const float gfd    = (dd - du) * 0.5f / (height + EPSF);
      const float a      = w * cgy[ga];
      gf[r] = (a * gy[ga] + cfd * gfd) / (a + cfd + EPSF);
      cf[r] = (a + cfd) * inv_w1;
    }

    // ---- 3x3 patch sum (col neighbors via shuffles) ----
    const long sbase = (long)(b * C_ + c) * 9 * (HO * WO) + (long)ho * WO + wo_c;
    float nom = 0.f, den = 0.f;
#pragma unroll
    for (int i = 0; i < 3; ++i) {
      const float g0 = gf[i],              c0 = cf[i];
      const float g1 = __shfl_down(g0, 1), c1 = __shfl_down(c0, 1);
      const float g2 = __shfl_down(g0, 2), c2 = __shfl_down(c0, 2);
      const float sp0 = spr[sbase + (long)(i * 3 + 0) * (HO * WO)];
      const float sp1 = spr[sbase + (long)(i * 3 + 1) * (HO * WO)];
      const float sp2 = spr[sbase + (long)(i * 3 + 2) * (HO * WO)];
      const float cp0 = c0 * sp0 * sw_s[c * 9 + i * 3 + 0];
      const float cp1 = c1 * sp1 * sw_s[c * 9 + i * 3 + 1];
      const float cp2 = c2 * sp2 * sw_s[c * 9 + i * 3 + 2];
      nom += cp0 * g0 + cp1 * g1 + cp2 * g2;
      den += cp0 + cp1 + cp2;
    }
    const float gy_sp  = nom / (den + EPSF);
    const float cgy_sp = den * invSW;
    const float av     = gy_sp * cgy_sp;

    // ---- accumulate 1x1 channel mix ----
#pragma unroll
    for (int o = 0; o < O_; ++o) {
      const float wv = cw_s[o * C_ + c];   // uniform address -> broadcast
      n2[o] += av * wv;
      d2[o] += cgy_sp * wv;
    }
  }

  if (!valid) return;
#pragma unroll
  for (int o = 0; o < O_; ++o) {
    const long oidx = (long)(b * O_ + o) * (HO * WO) + (long)ho * WO + wo;
    out[oidx]        = n2[o] / (d2[o] + EPSF) + bias_s[o];
    out[OUT1 + oidx] = d2[o] * invCW;
  }
}

// ---------------------------------------------------------------------------
extern "C" void kernel_launch(void* const* d_in, const int* in_sizes, int n_in,
                              void* d_out, int out_size, void* d_ws, size_t ws_size,
                              hipStream_t stream) {
  const float* d      = (const float*)d_in[0];
  const float* cd     = (const float*)d_in[1];
  const float* s      = (const float*)d_in[2];
  // d_in[3]=cs, d_in[4]=gx, d_in[5]=cgx unused by the reference
  const float* gy     = (const float*)d_in[6];
  const float* cgy    = (const float*)d_in[7];
  const float* spr    = (const float*)d_in[8];
  const float* w_prop = (const float*)d_in[9];
  const float* spw    = (const float*)d_in[10];
  const float* chw    = (const float*)d_in[11];
  const float* bias   = (const float*)d_in[12];
  float* out = (float*)d_out;

  float* params = (float*)d_ws;

  k_setup<<<1, 256, 0, stream>>>(w_prop, spw, chw, params);

  const int nblk = (NWAVE + 3) / 4;  // 4 waves per 256-thread block -> 1143
  k_fused<<<nblk, 256, 0, stream>>>(d, cd, s, gy, cgy, spr, params, bias, out);
}

// Round 4
// 170.267 us; speedup vs baseline: 1.1839x; 1.1839x over previous
//
#include <hip/hip_runtime.h>

#define EPSF 1e-20f

typedef float v2f __attribute__((ext_vector_type(2)));

constexpr int B_ = 2, C_ = 32, O_ = 32, H_ = 256, W_ = 512;
constexpr int HO = 254, WO = 510;
constexpr int TH = 8;              // output rows per block
constexpr int WT = 32;             // output cols per block
constexpr int TROW = TH + 2;       // 10 staged gf rows
constexpr int TCOL = WT + 2;       // 34 staged gf cols
constexpr int NPOS = TROW * TCOL;  // 340
constexpr int HW  = H_ * W_;       // 131072
constexpr int PLO = HO * WO;       // 129540
constexpr int OUT1 = B_ * O_ * PLO;

__device__ __forceinline__ float sp_(float x) { return log1pf(expf(x)); }
__device__ __forceinline__ float rcp_(float x) { return __builtin_amdgcn_rcpf(x); }

// ---------------------------------------------------------------------------
// Setup: softplus weights + reductions into params.
// Layout (floats): [0]=w [1]=sum(sw) [2]=sum(cw)
//   [16..304)   = sw (C*9, row-major [c][k])
//   [304..1328) = cw TRANSPOSED [c][o]  (cw_T[c*32+o] = softplus(chw[o*32+c]))
// ---------------------------------------------------------------------------
__global__ __launch_bounds__(256) void k_setup(const float* __restrict__ w_prop,
                                               const float* __restrict__ spw,
                                               const float* __restrict__ chw,
                                               float* __restrict__ params) {
  __shared__ float red[256];
  int t = threadIdx.x;
  float l1 = 0.f;
  for (int i = t; i < 288; i += 256) { float v = sp_(spw[i]); params[16 + i] = v; l1 += v; }
  red[t] = l1; __syncthreads();
  for (int k = 128; k > 0; k >>= 1) { if (t < k) red[t] += red[t + k]; __syncthreads(); }
  float SW = red[0]; __syncthreads();
  float l2 = 0.f;
  for (int i = t; i < 1024; i += 256) {
    int o = i >> 5, c = i & 31;
    float v = sp_(chw[o * C_ + c]);
    params[304 + c * O_ + o] = v;   // transposed store
    l2 += v;
  }
  red[t] = l2; __syncthreads();
  for (int k = 128; k > 0; k >>= 1) { if (t < k) red[t] += red[t + k]; __syncthreads(); }
  if (t == 0) { params[0] = sp_(w_prop[0]); params[1] = SW; params[2] = red[0]; }
}

// ---------------------------------------------------------------------------
// Fused kernel, software-pipelined channel loop:
//   stage(c) from prefetched regs -> LDS buf[c&1]
//   issue ALL loads for channel c+1 (18 raw + 9 spr)
//   __syncthreads()                      (one barrier per channel)
//   consume(c): 3x3 patch from LDS + pk-fma channel mix
// ---------------------------------------------------------------------------
struct Raw { float du, dd, su, sb, sd, cu, cdn, gyv, cgyv; };

__global__ __launch_bounds__(256) void k_fused(const float* __restrict__ d,
                                               const float* __restrict__ cd,
                                               const float* __restrict__ s,
                                               const float* __restrict__ gy,
                                               const float* __restrict__ cgy,
                                               const float* __restrict__ spr,
                                               const float* __restrict__ params,
                                               const float* __restrict__ bias,
                                               float* __restrict__ out) {
  __shared__ v2f tile[2][NPOS];

  const int b   = blockIdx.z;
  const int ho0 = blockIdx.y * TH;
  const int wo0 = blockIdx.x * WT;
  const int t   = threadIdx.x;

  const float w      = params[0];          // uniform -> s_load
  const float inv_w1 = rcp_(w + 1.0f);
  const float invSW  = rcp_(params[1]);
  const float invCW  = rcp_(params[2]);

  // ---- staging position(s) for this thread (slot0 always, slot1 if t<84) ----
  const bool has1 = (t < NPOS - 256);
  int bo[2], uo[2], doo[2];
  float mu[2], md[2], pv[2];
#pragma unroll
  for (int sl = 0; sl < 2; ++sl) {
    const int pos = t + sl * 256;
    const int r  = pos / TCOL;
    const int cc = pos - r * TCOL;
    const int gh = ho0 + r;
    const int gw = wo0 + cc;
    const bool ok = (pos < NPOS) && (gh < H_) && (gw < W_);
    const int ghc = ok ? gh : 0;
    const int gwc = ok ? gw : 0;
    const int base = ghc * W_ + gwc;
    bo[sl]  = base;
    uo[sl]  = (ghc == 0)      ? base + (H_ - 1) * W_ : base - W_;
    doo[sl] = (ghc == H_ - 1) ? base - (H_ - 1) * W_ : base + W_;
    mu[sl]  = (ghc == 0)      ? 0.f : 1.f;
    md[sl]  = (ghc == H_ - 1) ? 0.f : 1.f;
    pv[sl]  = ok ? 1.f : 0.f;
  }

  const int tr = t >> 5;          // 0..7
  const int tw = t & 31;          // 0..31
  const int ho = ho0 + tr;
  const int wo = wo0 + tw;
  const bool valid = (ho < HO) && (wo < WO);
  const int ho_c = valid ? ho : 0;
  const int wo_c = valid ? wo : 0;

  const int cpl0   = b * C_ * HW;
  const int sbase0 = b * C_ * 9 * PLO + ho_c * WO + wo_c;

  auto load_raw = [&](int cpl, int sl, Raw& R) {
    R.du   = d[cpl + uo[sl]];
    R.dd   = d[cpl + doo[sl]];
    R.su   = s[cpl + uo[sl]];
    R.sb   = s[cpl + bo[sl]];
    R.sd   = s[cpl + doo[sl]];
    R.cu   = cd[cpl + uo[sl]];
    R.cdn  = cd[cpl + doo[sl]];
    R.gyv  = gy[cpl + bo[sl]];
    R.cgyv = cgy[cpl + bo[sl]];
  };

  auto stage1 = [&](const Raw& R, int sl) -> v2f {
    const float cu  = R.cu * mu[sl];
    const float cdn = R.cdn * md[sl];
    const float cfd = R.sb * R.su * R.sd * cu * cu;        // cd_up twice (faithful)
    const float height = (cu * R.du + cdn * R.dd) * rcp_(cu + cdn + EPSF);
    const float gfd = (R.dd - R.du) * 0.5f * rcp_(height + EPSF);
    const float a = w * R.cgyv;
    const float vg = (a * R.gyv + cfd * gfd) * rcp_(a + cfd + EPSF);
    const float vc = (a + cfd) * inv_w1;
    return (v2f){vg * pv[sl], vc * pv[sl]};
  };

  // ---- prologue: prefetch channel 0 ----
  Raw R0, R1;
  float spn[9];
  load_raw(cpl0, 0, R0);
  if (has1) load_raw(cpl0, 1, R1);
#pragma unroll
  for (int k = 0; k < 9; ++k) spn[k] = spr[sbase0 + k * PLO];

  v2f acc[O_];
#pragma unroll
  for (int o = 0; o < O_; ++o) acc[o] = (v2f){0.f, 0.f};

  for (int c = 0; c < C_; ++c) {
    v2f* buf = tile[c & 1];
    // ---- stage(c) from regs ----
    buf[t] = stage1(R0, 0);
    if (has1) buf[t + 256] = stage1(R1, 1);

    // ---- keep spr(c), issue all loads for c+1 ----
    float spv[9];
#pragma unroll
    for (int k = 0; k < 9; ++k) spv[k] = spn[k];
    const int cn = (c + 1 < C_) ? c + 1 : c;     // last iter: harmless reload
    const int cpl_n = cpl0 + cn * HW;
    load_raw(cpl_n, 0, R0);
    if (has1) load_raw(cpl_n, 1, R1);
    const int sb_n = sbase0 + cn * 9 * PLO;
#pragma unroll
    for (int k = 0; k < 9; ++k) spn[k] = spr[sb_n + k * PLO];

    __syncthreads();   // buf[c&1] ready; also fences reuse (see note)

    // ---- consume(c) ----
    const float* swc = params + 16 + c * 9;       // uniform -> s_load
    float nom = 0.f, den = 0.f;
#pragma unroll
    for (int i = 0; i < 3; ++i) {
#pragma unroll
      for (int j = 0; j < 3; ++j) {
        const v2f g = buf[(tr + i) * TCOL + tw + j];   // ds_read_b64
        const float cp = g.y * spv[i * 3 + j] * swc[i * 3 + j];
        nom += cp * g.x;
        den += cp;
      }
    }
    const float gy_sp  = nom * rcp_(den + EPSF);
    const float cgy_sp = den * invSW;
    const v2f av2 = {gy_sp * cgy_sp, cgy_sp};

    const float* cwc = params + 304 + c * O_;     // transposed row, uniform
#pragma unroll
    for (int o = 0; o < O_; ++o) acc[o] += av2 * cwc[o];   // v_pk_fma_f32
  }

  if (!valid) return;
  const int obase = b * O_ * PLO + ho * WO + wo;
#pragma unroll
  for (int o = 0; o < O_; ++o) {
    out[obase + o * PLO]        = acc[o].x / (acc[o].y + EPSF) + bias[o];
    out[OUT1 + obase + o * PLO] = acc[o].y * invCW;
  }
}

// ---------------------------------------------------------------------------
extern "C" void kernel_launch(void* const* d_in, const int* in_sizes, int n_in,
                              void* d_out, int out_size, void* d_ws, size_t ws_size,
                              hipStream_t stream) {
  const float* d      = (const float*)d_in[0];
  const float* cd     = (const float*)d_in[1];
  const float* s      = (const float*)d_in[2];
  // d_in[3]=cs, d_in[4]=gx, d_in[5]=cgx unused by the reference
  const float* gy     = (const float*)d_in[6];
  const float* cgy    = (const float*)d_in[7];
  const float* spr    = (const float*)d_in[8];
  const float* w_prop = (const float*)d_in[9];
  const float* spw    = (const float*)d_in[10];
  const float* chw    = (const float*)d_in[11];
  const float* bias   = (const float*)d_in[12];
  float* out = (float*)d_out;

  float* params = (float*)d_ws;

  k_setup<<<1, 256, 0, stream>>>(w_prop, spw, chw, params);

  dim3 g((WO + WT - 1) / WT, (HO + TH - 1) / TH, B_);  // (16, 32, 2) = 1024 blocks
  k_fused<<<g, 256, 0, stream>>>(d, cd, s, gy, cgy, spr, params, bias, out);
}

// Round 5
// 149.037 us; speedup vs baseline: 1.3526x; 1.1424x over previous
//
#include <hip/hip_runtime.h>

#define EPSF 1e-20f

typedef float v2f __attribute__((ext_vector_type(2)));

constexpr int B_ = 2, C_ = 32, O_ = 32, H_ = 256, W_ = 512;
constexpr int HO = 254, WO = 510;
constexpr int HW  = H_ * W_;        // 131072
constexpr int PLO = HO * WO;        // 129540
constexpr int OUT1 = B_ * O_ * PLO;
constexpr int IMG  = B_ * C_ * HW;  // 8,388,608
constexpr int WT2  = 64;            // K2 tile width (pixels per block)

__device__ __forceinline__ float sp_(float x) { return log1pf(expf(x)); }
__device__ __forceinline__ float rcp_(float x) { return __builtin_amdgcn_rcpf(x); }

// pack two floats as bf16(RN) into one uint: low16 = g, high16 = c
__device__ __forceinline__ unsigned bfpack(float g, float c) {
  unsigned ug = __float_as_uint(g);
  unsigned uc = __float_as_uint(c);
  ug = ug + 0x7FFFu + ((ug >> 16) & 1u);
  uc = uc + 0x7FFFu + ((uc >> 16) & 1u);
  return (ug >> 16) | (uc & 0xFFFF0000u);
}
__device__ __forceinline__ float bf_lo(unsigned u) { return __uint_as_float(u << 16); }
__device__ __forceinline__ float bf_hi(unsigned u) { return __uint_as_float(u & 0xFFFF0000u); }

// ---------------------------------------------------------------------------
// Setup: softplus weights + reductions into params.
// Layout (floats): [0]=w [1]=sum(sw) [2]=sum(cw)
//   [16..304)   = sw[c][k]           (C*9)
//   [304..1328) = cwT[c][o]          (transposed: cwT[c*32+o] = softplus(chw[o*32+c]))
// ---------------------------------------------------------------------------
__global__ __launch_bounds__(256) void k_setup(const float* __restrict__ w_prop,
                                               const float* __restrict__ spw,
                                               const float* __restrict__ chw,
                                               float* __restrict__ params) {
  __shared__ float red[256];
  int t = threadIdx.x;
  float l1 = 0.f;
  for (int i = t; i < 288; i += 256) { float v = sp_(spw[i]); params[16 + i] = v; l1 += v; }
  red[t] = l1; __syncthreads();
  for (int k = 128; k > 0; k >>= 1) { if (t < k) red[t] += red[t + k]; __syncthreads(); }
  float SW = red[0]; __syncthreads();
  float l2 = 0.f;
  for (int i = t; i < 1024; i += 256) {
    int o = i >> 5, c = i & 31;
    float v = sp_(chw[o * C_ + c]);
    params[304 + c * O_ + o] = v;
    l2 += v;
  }
  red[t] = l2; __syncthreads();
  for (int k = 128; k > 0; k >>= 1) { if (t < k) red[t] += red[t + k]; __syncthreads(); }
  if (t == 0) { params[0] = sp_(w_prop[0]); params[1] = SW; params[2] = red[0]; }
}

// ---------------------------------------------------------------------------
// K1: per-pixel vertical fusion -> packed bf16 (gy_f, cgy_f), float4 in,
// uint4 out. Pure streaming, no barriers.
// ---------------------------------------------------------------------------
__global__ __launch_bounds__(256) void k1_gyf(const float* __restrict__ d,
                                              const float* __restrict__ cd,
                                              const float* __restrict__ s,
                                              const float* __restrict__ gy,
                                              const float* __restrict__ cgy,
                                              const float* __restrict__ params,
                                              unsigned* __restrict__ I) {
  const float w      = params[0];
  const float inv_w1 = rcp_(w + 1.0f);
  const int idx = blockIdx.x * 256 + threadIdx.x;
  const long i4 = (long)idx * 4;
  const int h = (int)((i4 >> 9) & (H_ - 1));
  const long up = (h == 0)      ? i4 + (long)(H_ - 1) * W_ : i4 - W_;
  const long dn = (h == H_ - 1) ? i4 - (long)(H_ - 1) * W_ : i4 + W_;

  float4 duv = *(const float4*)(d + up);
  float4 ddv = *(const float4*)(d + dn);
  float4 sv  = *(const float4*)(s + i4);
  float4 suv = *(const float4*)(s + up);
  float4 sdv = *(const float4*)(s + dn);
  float4 cduv = (h == 0)      ? make_float4(0.f, 0.f, 0.f, 0.f) : *(const float4*)(cd + up);
  float4 cddv = (h == H_ - 1) ? make_float4(0.f, 0.f, 0.f, 0.f) : *(const float4*)(cd + dn);
  float4 gyv  = *(const float4*)(gy + i4);
  float4 cgyv = *(const float4*)(cgy + i4);

  const float* pdu = (const float*)&duv;  const float* pdd = (const float*)&ddv;
  const float* ps  = (const float*)&sv;   const float* psu = (const float*)&suv;
  const float* psd = (const float*)&sdv;  const float* pcu = (const float*)&cduv;
  const float* pcd = (const float*)&cddv; const float* pg  = (const float*)&gyv;
  const float* pc  = (const float*)&cgyv;

  uint4 o;
  unsigned* po = (unsigned*)&o;
#pragma unroll
  for (int j = 0; j < 4; ++j) {
    const float cu = pcu[j], cdn = pcd[j];
    const float cfd = ps[j] * psu[j] * psd[j] * cu * cu;           // cd_up twice (faithful)
    const float height = (cu * pdu[j] + cdn * pdd[j]) * rcp_(cu + cdn + EPSF);
    const float gfd = (pdd[j] - pdu[j]) * 0.5f * rcp_(height + EPSF);
    const float a = w * pc[j];
    const float vg = (a * pg[j] + cfd * gfd) * rcp_(a + cfd + EPSF);
    const float vc = (a + cfd) * inv_w1;
    po[j] = bfpack(vg, vc);
  }
  *(uint4*)(I + i4) = o;
}

// ---------------------------------------------------------------------------
// K2: fused 3x3 grouped conv + 1x1 channel mix.
// Block = 256 threads = (b, ho, 64-wide wo tile). Grid (8, 254, 2) = 4064.
// Phase A: thread = (pixel-pair pp, channel-group cg of 4 channels);
//          uint2 loads of packed gf/cf, float2 loads of spr -> AB[c][px] LDS.
// Phase B: thread = (px, o-group); 32x ds_read_b64 + v_pk_fma channel mix;
//          weights via wave-uniform s_loads from params (cwT) and bias.
// ---------------------------------------------------------------------------
__global__ __launch_bounds__(256) void k2_fused(const unsigned* __restrict__ I,
                                                const float* __restrict__ spr,
                                                const float* __restrict__ params,
                                                const float* __restrict__ bias,
                                                float* __restrict__ out) {
  __shared__ float sw_s[288];
  __shared__ v2f AB[C_][WT2 + 2];   // [c][px], pad 2 -> 66 v2f per row

  const int b   = blockIdx.z;
  const int ho  = blockIdx.y;
  const int wo0 = blockIdx.x * WT2;
  const int t   = threadIdx.x;

  for (int i = t; i < 288; i += 256) sw_s[i] = params[16 + i];
  const float invSW = rcp_(params[1]);
  const float invCW = rcp_(params[2]);
  __syncthreads();

  // ---- Phase A ----
  const int pp = t & 31;         // pixel pair: px = 2pp, 2pp+1
  const int cg = t >> 5;         // 0..7 -> channels cg*4 .. cg*4+3
  const int wo  = wo0 + 2 * pp;
  const int wos = (wo <= WO - 2) ? wo : (WO - 2);   // even clamp (508)

#pragma unroll
  for (int ci = 0; ci < 4; ++ci) {
    const int c = cg * 4 + ci;
    const unsigned* Ip = I + (b * C_ + c) * HW + ho * W_ + wos;
    uint2 r0a = *(const uint2*)(Ip);
    uint2 r0b = *(const uint2*)(Ip + 2);
    uint2 r1a = *(const uint2*)(Ip + W_);
    uint2 r1b = *(const uint2*)(Ip + W_ + 2);
    uint2 r2a = *(const uint2*)(Ip + 2 * W_);
    uint2 r2b = *(const uint2*)(Ip + 2 * W_ + 2);

    const float* sp = spr + (long)(b * C_ + c) * 9 * PLO + ho * WO + wos;
    v2f spv[9];
#pragma unroll
    for (int k = 0; k < 9; ++k) spv[k] = *(const v2f*)(sp + (long)k * PLO);

    unsigned urow[3][4] = {{r0a.x, r0a.y, r0b.x, r0b.y},
                           {r1a.x, r1a.y, r1b.x, r1b.y},
                           {r2a.x, r2a.y, r2b.x, r2b.y}};
    float gf[3][4], cf[3][4];
#pragma unroll
    for (int i = 0; i < 3; ++i)
#pragma unroll
      for (int j = 0; j < 4; ++j) { gf[i][j] = bf_lo(urow[i][j]); cf[i][j] = bf_hi(urow[i][j]); }

#pragma unroll
    for (int u = 0; u < 2; ++u) {      // the two pixels of the pair
      float nom = 0.f, den = 0.f;
#pragma unroll
      for (int i = 0; i < 3; ++i) {
#pragma unroll
        for (int j = 0; j < 3; ++j) {
          const float cp = cf[i][u + j] * spv[i * 3 + j][u] * sw_s[c * 9 + i * 3 + j];
          nom += cp * gf[i][u + j];
          den += cp;
        }
      }
      const float gy_sp  = nom * rcp_(den + EPSF);
      const float cgy_sp = den * invSW;
      AB[c][2 * pp + u] = (v2f){gy_sp * cgy_sp, cgy_sp};
    }
  }
  __syncthreads();

  // ---- Phase B ----
  const int px  = t & 63;
  const int og  = __builtin_amdgcn_readfirstlane(t >> 6);  // 0..3, wave-uniform
  const int wob = wo0 + px;

  v2f ab[C_];
#pragma unroll
  for (int c = 0; c < C_; ++c) ab[c] = AB[c][px];

  const float* cwT = params + 304;     // [c][o], uniform indices -> s_load
  v2f acc[8];
#pragma unroll
  for (int oj = 0; oj < 8; ++oj) acc[oj] = (v2f){0.f, 0.f};
#pragma unroll
  for (int c = 0; c < C_; ++c) {
#pragma unroll
    for (int oj = 0; oj < 8; ++oj)
      acc[oj] += ab[c] * cwT[c * O_ + og * 8 + oj];   // v_pk_fma_f32
  }

  if (wob < WO) {
    const int obase = b * O_ * PLO + ho * WO + wob;
#pragma unroll
    for (int oj = 0; oj < 8; ++oj) {
      const int o = og * 8 + oj;
      out[obase + o * PLO]        = acc[oj].x * rcp_(acc[oj].y + EPSF) + bias[o];
      out[OUT1 + obase + o * PLO] = acc[oj].y * invCW;
    }
  }
}

// ---------------------------------------------------------------------------
extern "C" void kernel_launch(void* const* d_in, const int* in_sizes, int n_in,
                              void* d_out, int out_size, void* d_ws, size_t ws_size,
                              hipStream_t stream) {
  const float* d      = (const float*)d_in[0];
  const float* cd     = (const float*)d_in[1];
  const float* s      = (const float*)d_in[2];
  // d_in[3]=cs, d_in[4]=gx, d_in[5]=cgx unused by the reference
  const float* gy     = (const float*)d_in[6];
  const float* cgy    = (const float*)d_in[7];
  const float* spr    = (const float*)d_in[8];
  const float* w_prop = (const float*)d_in[9];
  const float* spw    = (const float*)d_in[10];
  const float* chw    = (const float*)d_in[11];
  const float* bias   = (const float*)d_in[12];
  float* out = (float*)d_out;

  float* params = (float*)d_ws;                       // 4096 floats reserved
  unsigned* I   = (unsigned*)d_ws + 4096;             // packed bf16 intermediate (33.5 MB)

  k_setup<<<1, 256, 0, stream>>>(w_prop, spw, chw, params);

  k1_gyf<<<IMG / 4 / 256, 256, 0, stream>>>(d, cd, s, gy, cgy, params, I);

  dim3 g2(8, HO, B_);   // (8, 254, 2) = 4064 blocks
  k2_fused<<<g2, 256, 0, stream>>>(I, spr, params, bias, out);
}